// Round 1
// 910.102 us; speedup vs baseline: 1.1407x; 1.1407x over previous
//
#include <hip/hip_runtime.h>
#include <hip/hip_bf16.h>
#include <math.h>

#define T 2048
#define C 128
#define BATCH 8
#define NLAYER 10

typedef short bf16x8 __attribute__((ext_vector_type(8)));
typedef float f32x4 __attribute__((ext_vector_type(4)));
typedef unsigned short u16x4 __attribute__((ext_vector_type(4)));

__device__ __forceinline__ float sigmoidf_(float x) {
    return 1.f / (1.f + __expf(-x));
}
__device__ __forceinline__ float tanhf_(float x) {
    float a = fabsf(x);
    float e = __expf(-2.f * a);
    float t = (1.f - e) / (1.f + e);
    return copysignf(t, x);
}
__device__ __forceinline__ ushort f2bf(float v) {
    __hip_bfloat16 h = __float2bfloat16(v);
    return *reinterpret_cast<ushort*>(&h);
}
__device__ __forceinline__ float bf2f(ushort u) {
    unsigned int x = ((unsigned int)u) << 16;
    return __uint_as_float(x);
}

// ---------------- init: h = x*Wc + bc (f32 + bf16) ; skip = 0 ----------------
__global__ void k_init(const float* __restrict__ x, const float* __restrict__ Wc,
                       const float* __restrict__ bc, float* __restrict__ h32,
                       ushort* __restrict__ hb, float* __restrict__ skip) {
    int i = blockIdx.x * 256 + threadIdx.x;   // over B*T*C
    int c = i & 127;
    int pos = i >> 7;
    float v = x[pos] * Wc[c] + bc[c];
    h32[i] = v;
    hb[i] = f2bf(v);
    skip[i] = 0.f;
}

// ---------------- weight preps (one-time, bf16 transposed) ----------------
// WGb[l][n 0..255][k = j*128+ci]:  n<128 -> Wt col n ; n>=128 -> Ws col n-128
__global__ void k_prep_wg(const float* __restrict__ Wt, const float* __restrict__ Ws,
                          ushort* __restrict__ WGb) {
    int n = blockIdx.x;           // 0..255
    int l = blockIdx.y;
    int t = threadIdx.x;          // 0..383 : j = t>>7, ci = t&127
    int j = t >> 7, ci = t & 127;
    const float* src = (n < 128) ? Wt : Ws;
    int col = n & 127;
    WGb[((size_t)(l * 256 + n)) * 384 + t] = f2bf(src[(((size_t)l * 3 + j) * 128 + ci) * 128 + col]);
}
// WRb[l][n 0..255][ci]: n<128 -> Wskip col n ; n>=128 -> Wres col n-128
__global__ void k_prep_wr(const float* __restrict__ Wskip, const float* __restrict__ Wres,
                          ushort* __restrict__ WRb) {
    int n = blockIdx.x;
    int l = blockIdx.y;
    int ci = threadIdx.x;         // 0..127
    const float* src = (n < 128) ? Wskip : Wres;
    int col = n & 127;
    WRb[((size_t)(l * 256 + n)) * 128 + ci] = f2bf(src[((size_t)l * 128 + ci) * 128 + col]);
}
// W [3][KIN][N] f32 -> Wb [N][3*KIN] bf16; grid.x = N (head weights)
template<int KIN>
__global__ void k_prep_w(const float* __restrict__ W, ushort* __restrict__ Wb, int N) {
    int n = blockIdx.x;
    for (int k = threadIdx.x; k < 3 * KIN; k += blockDim.x)
        Wb[(size_t)n * (3 * KIN) + k] = f2bf(W[(size_t)k * N + n]);
}
__global__ void k_f32_to_bf16(const float* __restrict__ in, ushort* __restrict__ out, int n) {
    int i = blockIdx.x * 256 + threadIdx.x;
    if (i < n) out[i] = f2bf(in[i]);
}

// ---------------- conditioning precompute (5-layer chunk), float4 streaming ----------------
// z0[ll][b][t][n] bf16 = conv-bias + B + sum_c cond[b,c]*D[l,c,t,k]
// n<128: tanh branch (Dt/Bt/bt), n>=128: sigmoid branch (Ds/Bs/bs)
// thread = (k4 = 4 consecutive channels, tq = t within 8-t tile); all 8 batches in regs.
__global__ __launch_bounds__(256) void k_cond(
    const float* __restrict__ cond,
    const float* __restrict__ Dt, const float* __restrict__ Bt,
    const float* __restrict__ Ds, const float* __restrict__ Bs,
    const float* __restrict__ bt, const float* __restrict__ bs,
    ushort* __restrict__ z0, int l0)
{
    const int l  = l0 + blockIdx.y;
    const int ll = blockIdx.y;
    const int k4 = (threadIdx.x & 31) * 4;   // channel group 0..124
    const int tq = threadIdx.x >> 5;         // 0..7
    const int t  = blockIdx.x * 8 + tq;

    __shared__ float sc[128];
    if (threadIdx.x < 128) sc[threadIdx.x] = cond[threadIdx.x];
    __syncthreads();

    const f32x4 btv = *(const f32x4*)(bt + l * 128 + k4);
    const f32x4 bsv = *(const f32x4*)(bs + l * 128 + k4);
    const f32x4 Btv = *(const f32x4*)(Bt + ((size_t)l * T + t) * 128 + k4);
    const f32x4 Bsv = *(const f32x4*)(Bs + ((size_t)l * T + t) * 128 + k4);

    f32x4 zt[8], zs[8];
    #pragma unroll
    for (int b = 0; b < 8; ++b) {
        zt[b] = btv + Btv;
        zs[b] = bsv + Bsv;
    }

    const float* dtp = Dt + (((size_t)l * 16) * T + t) * 128 + k4;
    const float* dsp = Ds + (((size_t)l * 16) * T + t) * 128 + k4;
    #pragma unroll
    for (int c = 0; c < 16; ++c) {
        const f32x4 dv = *(const f32x4*)(dtp + (size_t)c * T * 128);
        const f32x4 sv = *(const f32x4*)(dsp + (size_t)c * T * 128);
        #pragma unroll
        for (int b = 0; b < 8; ++b) {
            const float cb = sc[b * 16 + c];
            zt[b] += cb * dv;
            zs[b] += cb * sv;
        }
    }

    #pragma unroll
    for (int b = 0; b < 8; ++b) {
        size_t zb = (((size_t)ll * 8 + b) * T + t) * 256;
        u16x4 pt, ps;
        #pragma unroll
        for (int j = 0; j < 4; ++j) {
            pt[j] = f2bf(zt[b][j]);
            ps[j] = f2bf(zs[b][j]);
        }
        *(u16x4*)(z0 + zb + k4)       = pt;
        *(u16x4*)(z0 + zb + 128 + k4) = ps;
    }
}

// ---------------- fused MFMA WaveNet layer ----------------
// grid 512 (t-tile of 4, all 8 batches -> M=32 rows, r = p*8+b), block 256 (4 waves)
// wave w owns n = w*64 .. w*64+63 across all 32 rows.
// GEMM1: A = h taps (3 LDS segs), B = WG[l] (global, L2-hot), N=256=[t||s], K=384
// epilogue: +z0, exchange via LDS, gate, GEMM2 (g x WR[l], K=128) -> skip/res
__global__ __launch_bounds__(256) void k_gate(
    const float* __restrict__ h32_in, float* __restrict__ h32_out,
    const ushort* __restrict__ hb_in, ushort* __restrict__ hb_out,
    float* __restrict__ skip32,
    const ushort* __restrict__ WG,   // [256][384] (layer slice)
    const ushort* __restrict__ WR,   // [256][128]
    const ushort* __restrict__ z0l,  // [8][T][256]
    const float* __restrict__ bskip, const float* __restrict__ bres, // [128] slices
    int d)
{
    __shared__ ushort lds[3 * 32 * 136];   // 13056 ushorts = 26112 B
    // region reuse: zbuf = lds[0 .. 32*264)  (after GEMM1); gbuf = lds + 8704 (seg-2 area)
    const int tid  = threadIdx.x;
    const int lane = tid & 63, ln16 = lane & 15, quad = lane >> 4;
    const int wave = tid >> 6;
    const int n_off = wave * 64;
    const int t0 = blockIdx.x * 4;

    // stage A: 3 segs x 32 rows x 256 B
    #pragma unroll
    for (int it = 0; it < 6; ++it) {
        int task = tid + it * 256;        // [0, 1536)
        int part = task & 15;
        int r = (task >> 4) & 31;
        int j = task >> 9;
        int t = t0 + (r >> 3) + (j - 1) * d;
        int b = r & 7;
        uint4 v = make_uint4(0u, 0u, 0u, 0u);
        if (t >= 0 && t < T) v = *(const uint4*)(hb_in + ((size_t)b * T + t) * 128 + part * 8);
        *(uint4*)(&lds[(j * 32 + r) * 136 + part * 8]) = v;
    }
    __syncthreads();

    f32x4 acc[2][4];
    #pragma unroll
    for (int mt = 0; mt < 2; ++mt)
        #pragma unroll
        for (int nt = 0; nt < 4; ++nt)
            acc[mt][nt] = (f32x4){0.f, 0.f, 0.f, 0.f};

    #pragma unroll
    for (int j = 0; j < 3; ++j) {
        #pragma unroll
        for (int kc = 0; kc < 4; ++kc) {
            bf16x8 af[2], bfr[4];
            #pragma unroll
            for (int mt = 0; mt < 2; ++mt)
                af[mt] = *(const bf16x8*)(&lds[(j * 32 + mt * 16 + ln16) * 136 + kc * 32 + quad * 8]);
            #pragma unroll
            for (int nt = 0; nt < 4; ++nt)
                bfr[nt] = *(const bf16x8*)(WG + (size_t)(n_off + nt * 16 + ln16) * 384 + j * 128 + kc * 32 + quad * 8);
            #pragma unroll
            for (int mt = 0; mt < 2; ++mt)
                #pragma unroll
                for (int nt = 0; nt < 4; ++nt)
                    acc[mt][nt] = __builtin_amdgcn_mfma_f32_16x16x32_bf16(af[mt], bfr[nt], acc[mt][nt], 0, 0, 0);
        }
    }
    __syncthreads();   // A segs dead

    // epilogue-1: add z0, stash pre-activations in zbuf (bf16)
    #pragma unroll
    for (int mt = 0; mt < 2; ++mt) {
        #pragma unroll
        for (int nt = 0; nt < 4; ++nt) {
            int n = n_off + nt * 16 + ln16;
            #pragma unroll
            for (int r4 = 0; r4 < 4; ++r4) {
                int row = mt * 16 + quad * 4 + r4;
                int b = row & 7, p = row >> 3;
                float z = acc[mt][nt][r4] + bf2f(z0l[((size_t)b * T + t0 + p) * 256 + n]);
                lds[row * 264 + n] = f2bf(z);
            }
        }
    }
    __syncthreads();

    // gate: g = tanh(zt) * sigmoid(zs) -> gbuf [32][136]
    {
        int r = tid >> 3;              // 0..31
        int k0 = (tid & 7) * 16;       // 0..127 step 16
        #pragma unroll
        for (int kk = 0; kk < 16; ++kk) {
            int k = k0 + kk;
            float zt = bf2f(lds[r * 264 + k]);
            float zs = bf2f(lds[r * 264 + 128 + k]);
            lds[8704 + r * 136 + k] = f2bf(tanhf_(zt) * sigmoidf_(zs));
        }
    }
    __syncthreads();

    // GEMM2: skip/res 1x1 convs, K=128
    f32x4 acc2[2][4];
    #pragma unroll
    for (int mt = 0; mt < 2; ++mt)
        #pragma unroll
        for (int nt = 0; nt < 4; ++nt)
            acc2[mt][nt] = (f32x4){0.f, 0.f, 0.f, 0.f};

    #pragma unroll
    for (int kc = 0; kc < 4; ++kc) {
        bf16x8 af[2], bfr[4];
        #pragma unroll
        for (int mt = 0; mt < 2; ++mt)
            af[mt] = *(const bf16x8*)(&lds[8704 + (mt * 16 + ln16) * 136 + kc * 32 + quad * 8]);
        #pragma unroll
        for (int nt = 0; nt < 4; ++nt)
            bfr[nt] = *(const bf16x8*)(WR + (size_t)(n_off + nt * 16 + ln16) * 128 + kc * 32 + quad * 8);
        #pragma unroll
        for (int mt = 0; mt < 2; ++mt)
            #pragma unroll
            for (int nt = 0; nt < 4; ++nt)
                acc2[mt][nt] = __builtin_amdgcn_mfma_f32_16x16x32_bf16(af[mt], bfr[nt], acc2[mt][nt], 0, 0, 0);
    }

    // epilogue-2: waves 0/1 (n<128) -> skip accum; waves 2/3 -> residual h
    #pragma unroll
    for (int mt = 0; mt < 2; ++mt) {
        #pragma unroll
        for (int nt = 0; nt < 4; ++nt) {
            int n = n_off + nt * 16 + ln16;
            int k = n & 127;
            #pragma unroll
            for (int r4 = 0; r4 < 4; ++r4) {
                int row = mt * 16 + quad * 4 + r4;
                int b = row & 7, p = row >> 3;
                size_t idx = ((size_t)b * T + t0 + p) * 128 + k;
                float v = acc2[mt][nt][r4];
                if (n < 128) {
                    skip32[idx] += v + bskip[k];
                } else {
                    float hv = v + bres[k] + h32_in[idx];
                    h32_out[idx] = hv;
                    hb_out[idx] = f2bf(hv);
                }
            }
        }
    }
}

// ---------------- MFMA conv head (unchanged structure from round 2) ----------------
template<int KIN, bool OUT_BF16>
__global__ __launch_bounds__(256) void k_conv_mfma(
    const ushort* __restrict__ A, const ushort* __restrict__ Wb,
    const float* __restrict__ bias, void* __restrict__ outv,
    int b_in_off, int b_out_off)
{
    constexpr int AS = 40;
    __shared__ ushort As[66 * AS];
    __shared__ ushort Bs[3 * 128 * AS];

    const int tid  = threadIdx.x;
    const int lane = tid & 63;
    const int ln16 = lane & 15;
    const int quad = lane >> 4;
    const int wave = tid >> 6;
    const int m_off = (wave & 1) * 32;
    const int n_off = (wave >> 1) * 64;

    const int t0 = blockIdx.x * 64;
    const int n0 = blockIdx.y * 128;
    const int bz = blockIdx.z;
    const int N  = gridDim.y * 128;

    const ushort* Ab = A + (size_t)(b_in_off + bz) * T * KIN;

    f32x4 acc[2][4];
    #pragma unroll
    for (int mi = 0; mi < 2; ++mi)
        #pragma unroll
        for (int ni = 0; ni < 4; ++ni)
            acc[mi][ni] = (f32x4){0.f, 0.f, 0.f, 0.f};

    for (int cc = 0; cc < KIN / 32; ++cc) {
        for (int idx = tid; idx < 66 * 4; idx += 256) {
            int r = idx >> 2, part = idx & 3;
            int t = t0 - 1 + r;
            uint4 v = make_uint4(0u, 0u, 0u, 0u);
            if (t >= 0 && t < T)
                v = *(const uint4*)(Ab + (size_t)t * KIN + cc * 32 + part * 8);
            *(uint4*)(&As[r * AS + part * 8]) = v;
        }
        #pragma unroll
        for (int it = 0; it < 6; ++it) {
            int idx = tid + it * 256;
            int jr = idx >> 2, part = idx & 3;
            int j = jr >> 7, n = jr & 127;
            uint4 v = *(const uint4*)(Wb + (size_t)(n0 + n) * (3 * KIN) + j * KIN + cc * 32 + part * 8);
            *(uint4*)(&Bs[jr * AS + part * 8]) = v;
        }
        __syncthreads();

        #pragma unroll
        for (int j = 0; j < 3; ++j) {
            bf16x8 af[2], bf[4];
            #pragma unroll
            for (int mi = 0; mi < 2; ++mi)
                af[mi] = *(const bf16x8*)(&As[(m_off + mi * 16 + ln16 + j) * AS + quad * 8]);
            #pragma unroll
            for (int ni = 0; ni < 4; ++ni)
                bf[ni] = *(const bf16x8*)(&Bs[(j * 128 + n_off + ni * 16 + ln16) * AS + quad * 8]);
            #pragma unroll
            for (int mi = 0; mi < 2; ++mi)
                #pragma unroll
                for (int ni = 0; ni < 4; ++ni)
                    acc[mi][ni] = __builtin_amdgcn_mfma_f32_16x16x32_bf16(af[mi], bf[ni], acc[mi][ni], 0, 0, 0);
        }
        __syncthreads();
    }

    #pragma unroll
    for (int ni = 0; ni < 4; ++ni) {
        int n = n0 + n_off + ni * 16 + ln16;
        float bv = bias[n];
        #pragma unroll
        for (int mi = 0; mi < 2; ++mi) {
            #pragma unroll
            for (int r = 0; r < 4; ++r) {
                int m = m_off + mi * 16 + quad * 4 + r;
                int t = t0 + m;
                float v = fmaxf(acc[mi][ni][r] + bv, 0.f);
                size_t oi = ((size_t)(b_out_off + bz) * T + t) * N + n;
                if constexpr (OUT_BF16) ((ushort*)outv)[oi] = f2bf(v);
                else                    ((float*)outv)[oi]  = v;
            }
        }
    }
}

// ---------------- head conv3: 256 -> 1, k=1, tanh ----------------
__global__ __launch_bounds__(256) void k_conv3(
    const float* __restrict__ out2, const float* __restrict__ W3,
    const float* __restrict__ b3, float* __restrict__ out)
{
    int wid = threadIdx.x >> 6, lane = threadIdx.x & 63;
    int pos = blockIdx.x * 4 + wid;
    float4 v = *(const float4*)(out2 + (size_t)pos * 256 + lane * 4);
    float4 w = *(const float4*)(W3 + lane * 4);
    float sum = v.x * w.x + v.y * w.y + v.z * w.z + v.w * w.w;
    #pragma unroll
    for (int off = 32; off > 0; off >>= 1) sum += __shfl_down(sum, off);
    if (lane == 0) out[pos] = tanhf_(sum + b3[0]);
}

extern "C" void kernel_launch(void* const* d_in, const int* in_sizes, int n_in,
                              void* d_out, int out_size, void* d_ws, size_t ws_size,
                              hipStream_t stream)
{
    const float* x     = (const float*)d_in[0];
    const float* cond  = (const float*)d_in[1];
    const float* Wc    = (const float*)d_in[2];
    const float* bc    = (const float*)d_in[3];
    const float* Wt    = (const float*)d_in[4];
    const float* bt    = (const float*)d_in[5];
    const float* Ws    = (const float*)d_in[6];
    const float* bs    = (const float*)d_in[7];
    const float* Dt    = (const float*)d_in[8];
    const float* Bt    = (const float*)d_in[9];
    const float* Ds    = (const float*)d_in[10];
    const float* Bs    = (const float*)d_in[11];
    const float* Wskip = (const float*)d_in[12];
    const float* bskip = (const float*)d_in[13];
    const float* Wres  = (const float*)d_in[14];
    const float* bres  = (const float*)d_in[15];
    const float* W1    = (const float*)d_in[16];
    const float* b1    = (const float*)d_in[17];
    const float* W2    = (const float*)d_in[18];
    const float* b2    = (const float*)d_in[19];
    const float* W3    = (const float*)d_in[20];
    const float* b3    = (const float*)d_in[21];
    float* out = (float*)d_out;

    float* ws = (float*)d_ws;
    float*  skip32 = ws;                       // 2M f32
    float*  h32a   = ws + 2097152;             // 2M f32
    float*  h32b   = ws + 4194304;             // 2M f32
    float*  out2   = ws + 6291456;             // 4M f32
    ushort* u      = (ushort*)(ws + 10485760);
    ushort* hba    = u;                        // 2M us
    ushort* hbb    = u + 2097152;              // 2M us
    ushort* WGb    = u + 4194304;              // 983,040 us
    ushort* WRb    = u + 5177344;              // 327,680 us
    ushort* W1b    = u + 5505024;              // 786,432 us
    ushort* W2b    = u + 6291456;              // 1,572,864 us
    ushort* skipb  = u + 7864320;              // 2M us
    ushort* z0     = u + 9961472;              // 5*8*T*256 = 20,971,520 us
    ushort* out1b  = z0;                       // reuses z0 region for the head

    // choose head batch chunk vs ws_size (z0 end needs ~103.8 MB; known ws >= 117 MB)
    int nb = 8;
    while (nb > 1) {
        size_t need = 41943040ull + 2ull * (9961472ull + (size_t)nb * 4194304ull);
        if (need <= ws_size) break;
        nb >>= 1;
    }

    k_init<<<8192, 256, 0, stream>>>(x, Wc, bc, h32a, hba, skip32);
    k_prep_wg<<<dim3(256, NLAYER), 384, 0, stream>>>(Wt, Ws, WGb);
    k_prep_wr<<<dim3(256, NLAYER), 128, 0, stream>>>(Wskip, Wres, WRb);
    k_prep_w<128><<<2048, 384, 0, stream>>>(W1, W1b, 2048);
    k_prep_w<2048><<<256, 1024, 0, stream>>>(W2, W2b, 256);

    static const int DIL[NLAYER] = {1, 2, 4, 8, 16, 32, 64, 128, 256, 512};
    float*  h32in = h32a;  float*  h32out = h32b;
    ushort* hbin  = hba;   ushort* hbout  = hbb;

    for (int chunk = 0; chunk < 2; ++chunk) {
        int l0 = chunk * 5;
        k_cond<<<dim3(T / 8, 5), 256, 0, stream>>>(cond, Dt, Bt, Ds, Bs, bt, bs, z0, l0);
        for (int l = l0; l < l0 + 5; ++l) {
            k_gate<<<512, 256, 0, stream>>>(
                h32in, h32out, hbin, hbout, skip32,
                WGb + (size_t)l * 256 * 384,
                WRb + (size_t)l * 256 * 128,
                z0 + (size_t)(l - l0) * 8 * T * 256,
                bskip + l * 128, bres + l * 128,
                DIL[l]);
            float* tf = h32in; h32in = h32out; h32out = tf;
            ushort* tu = hbin; hbin = hbout; hbout = tu;
        }
    }

    k_f32_to_bf16<<<(BATCH * T * C + 255) / 256, 256, 0, stream>>>(skip32, skipb, BATCH * T * C);

    for (int b0 = 0; b0 < BATCH; b0 += nb) {
        int nbc = (b0 + nb <= BATCH) ? nb : (BATCH - b0);
        k_conv_mfma<128, true><<<dim3(T / 64, 16, nbc), 256, 0, stream>>>(skipb, W1b, b1, out1b, b0, 0);
        k_conv_mfma<2048, false><<<dim3(T / 64, 2, nbc), 256, 0, stream>>>(out1b, W2b, b2, out2, 0, b0);
    }

    k_conv3<<<(BATCH * T) / 4, 256, 0, stream>>>(out2, W3, b3, out);
}

// Round 2
// 867.776 us; speedup vs baseline: 1.1964x; 1.0488x over previous
//
#include <hip/hip_runtime.h>
#include <hip/hip_bf16.h>
#include <math.h>

#define T 2048
#define C 128
#define BATCH 8
#define NLAYER 10

typedef short bf16x8 __attribute__((ext_vector_type(8)));
typedef float f32x4 __attribute__((ext_vector_type(4)));
typedef unsigned short u16x4 __attribute__((ext_vector_type(4)));

__device__ __forceinline__ float sigmoidf_(float x) {
    return 1.f / (1.f + __expf(-x));
}
__device__ __forceinline__ float tanhf_(float x) {
    float a = fabsf(x);
    float e = __expf(-2.f * a);
    float t = (1.f - e) / (1.f + e);
    return copysignf(t, x);
}
__device__ __forceinline__ ushort f2bf(float v) {
    __hip_bfloat16 h = __float2bfloat16(v);
    return *reinterpret_cast<ushort*>(&h);
}
__device__ __forceinline__ float bf2f(ushort u) {
    unsigned int x = ((unsigned int)u) << 16;
    return __uint_as_float(x);
}
// async global->LDS, 16B per lane; lds ptr must be wave-uniform (HW adds lane*16)
__device__ __forceinline__ void gl_lds16(const ushort* g, ushort* l) {
    __builtin_amdgcn_global_load_lds(
        (const __attribute__((address_space(1))) unsigned int*)g,
        (__attribute__((address_space(3))) unsigned int*)l, 16, 0, 0);
}

// ---------------- init: h = x*Wc + bc (f32 + bf16) ; skip = 0 ----------------
__global__ void k_init(const float* __restrict__ x, const float* __restrict__ Wc,
                       const float* __restrict__ bc, float* __restrict__ h32,
                       ushort* __restrict__ hb, float* __restrict__ skip) {
    int i = blockIdx.x * 256 + threadIdx.x;   // over B*T*C
    int c = i & 127;
    int pos = i >> 7;
    float v = x[pos] * Wc[c] + bc[c];
    h32[i] = v;
    hb[i] = f2bf(v);
    skip[i] = 0.f;
}

// ---------------- weight preps (one-time, bf16 transposed) ----------------
__global__ void k_prep_wg(const float* __restrict__ Wt, const float* __restrict__ Ws,
                          ushort* __restrict__ WGb) {
    int n = blockIdx.x;           // 0..255
    int l = blockIdx.y;
    int t = threadIdx.x;          // 0..383 : j = t>>7, ci = t&127
    int j = t >> 7, ci = t & 127;
    const float* src = (n < 128) ? Wt : Ws;
    int col = n & 127;
    WGb[((size_t)(l * 256 + n)) * 384 + t] = f2bf(src[(((size_t)l * 3 + j) * 128 + ci) * 128 + col]);
}
__global__ void k_prep_wr(const float* __restrict__ Wskip, const float* __restrict__ Wres,
                          ushort* __restrict__ WRb) {
    int n = blockIdx.x;
    int l = blockIdx.y;
    int ci = threadIdx.x;         // 0..127
    const float* src = (n < 128) ? Wskip : Wres;
    int col = n & 127;
    WRb[((size_t)(l * 256 + n)) * 128 + ci] = f2bf(src[((size_t)l * 128 + ci) * 128 + col]);
}
// W [3][KIN][N] f32 -> Wb [N][3*KIN] bf16; grid.x = N (head weights)
template<int KIN>
__global__ void k_prep_w(const float* __restrict__ W, ushort* __restrict__ Wb, int N) {
    int n = blockIdx.x;
    for (int k = threadIdx.x; k < 3 * KIN; k += blockDim.x)
        Wb[(size_t)n * (3 * KIN) + k] = f2bf(W[(size_t)k * N + n]);
}
__global__ void k_f32_to_bf16(const float* __restrict__ in, ushort* __restrict__ out, int n) {
    int i = blockIdx.x * 256 + threadIdx.x;
    if (i < n) out[i] = f2bf(in[i]);
}
// zero the two padding rows (pr=0 and pr=2049) per batch of out1p [8][2050][2048]
__global__ void k_zero_pad(ushort* __restrict__ out1p) {
    int i = blockIdx.x * 256 + threadIdx.x;      // [0, 16384) uints
    int ri = i >> 10, col = i & 1023;
    int b = ri >> 1, pr = (ri & 1) ? 2049 : 0;
    ((unsigned int*)out1p)[((size_t)b * 2050 + pr) * 1024 + col] = 0u;
}

// ---------------- conditioning precompute (5-layer chunk), float4 streaming ----------------
__global__ __launch_bounds__(256) void k_cond(
    const float* __restrict__ cond,
    const float* __restrict__ Dt, const float* __restrict__ Bt,
    const float* __restrict__ Ds, const float* __restrict__ Bs,
    const float* __restrict__ bt, const float* __restrict__ bs,
    ushort* __restrict__ z0, int l0)
{
    const int l  = l0 + blockIdx.y;
    const int ll = blockIdx.y;
    const int k4 = (threadIdx.x & 31) * 4;   // channel group 0..124
    const int tq = threadIdx.x >> 5;         // 0..7
    const int t  = blockIdx.x * 8 + tq;

    __shared__ float sc[128];
    if (threadIdx.x < 128) sc[threadIdx.x] = cond[threadIdx.x];
    __syncthreads();

    const f32x4 btv = *(const f32x4*)(bt + l * 128 + k4);
    const f32x4 bsv = *(const f32x4*)(bs + l * 128 + k4);
    const f32x4 Btv = *(const f32x4*)(Bt + ((size_t)l * T + t) * 128 + k4);
    const f32x4 Bsv = *(const f32x4*)(Bs + ((size_t)l * T + t) * 128 + k4);

    f32x4 zt[8], zs[8];
    #pragma unroll
    for (int b = 0; b < 8; ++b) {
        zt[b] = btv + Btv;
        zs[b] = bsv + Bsv;
    }

    const float* dtp = Dt + (((size_t)l * 16) * T + t) * 128 + k4;
    const float* dsp = Ds + (((size_t)l * 16) * T + t) * 128 + k4;
    #pragma unroll
    for (int c = 0; c < 16; ++c) {
        const f32x4 dv = *(const f32x4*)(dtp + (size_t)c * T * 128);
        const f32x4 sv = *(const f32x4*)(dsp + (size_t)c * T * 128);
        #pragma unroll
        for (int b = 0; b < 8; ++b) {
            const float cb = sc[b * 16 + c];
            zt[b] += cb * dv;
            zs[b] += cb * sv;
        }
    }

    #pragma unroll
    for (int b = 0; b < 8; ++b) {
        size_t zb = (((size_t)ll * 8 + b) * T + t) * 256;
        u16x4 pt, ps;
        #pragma unroll
        for (int j = 0; j < 4; ++j) {
            pt[j] = f2bf(zt[b][j]);
            ps[j] = f2bf(zs[b][j]);
        }
        *(u16x4*)(z0 + zb + k4)       = pt;
        *(u16x4*)(z0 + zb + 128 + k4) = ps;
    }
}

// ---------------- fused MFMA WaveNet layer ----------------
__global__ __launch_bounds__(256) void k_gate(
    const float* __restrict__ h32_in, float* __restrict__ h32_out,
    const ushort* __restrict__ hb_in, ushort* __restrict__ hb_out,
    float* __restrict__ skip32,
    const ushort* __restrict__ WG,   // [256][384] (layer slice)
    const ushort* __restrict__ WR,   // [256][128]
    const ushort* __restrict__ z0l,  // [8][T][256]
    const float* __restrict__ bskip, const float* __restrict__ bres, // [128] slices
    int d)
{
    __shared__ ushort lds[3 * 32 * 136];   // 13056 ushorts = 26112 B
    const int tid  = threadIdx.x;
    const int lane = tid & 63, ln16 = lane & 15, quad = lane >> 4;
    const int wave = tid >> 6;
    const int n_off = wave * 64;
    const int t0 = blockIdx.x * 4;

    // stage A: 3 segs x 32 rows x 256 B
    #pragma unroll
    for (int it = 0; it < 6; ++it) {
        int task = tid + it * 256;        // [0, 1536)
        int part = task & 15;
        int r = (task >> 4) & 31;
        int j = task >> 9;
        int t = t0 + (r >> 3) + (j - 1) * d;
        int b = r & 7;
        uint4 v = make_uint4(0u, 0u, 0u, 0u);
        if (t >= 0 && t < T) v = *(const uint4*)(hb_in + ((size_t)b * T + t) * 128 + part * 8);
        *(uint4*)(&lds[(j * 32 + r) * 136 + part * 8]) = v;
    }
    __syncthreads();

    f32x4 acc[2][4];
    #pragma unroll
    for (int mt = 0; mt < 2; ++mt)
        #pragma unroll
        for (int nt = 0; nt < 4; ++nt)
            acc[mt][nt] = (f32x4){0.f, 0.f, 0.f, 0.f};

    #pragma unroll
    for (int j = 0; j < 3; ++j) {
        #pragma unroll
        for (int kc = 0; kc < 4; ++kc) {
            bf16x8 af[2], bfr[4];
            #pragma unroll
            for (int mt = 0; mt < 2; ++mt)
                af[mt] = *(const bf16x8*)(&lds[(j * 32 + mt * 16 + ln16) * 136 + kc * 32 + quad * 8]);
            #pragma unroll
            for (int nt = 0; nt < 4; ++nt)
                bfr[nt] = *(const bf16x8*)(WG + (size_t)(n_off + nt * 16 + ln16) * 384 + j * 128 + kc * 32 + quad * 8);
            #pragma unroll
            for (int mt = 0; mt < 2; ++mt)
                #pragma unroll
                for (int nt = 0; nt < 4; ++nt)
                    acc[mt][nt] = __builtin_amdgcn_mfma_f32_16x16x32_bf16(af[mt], bfr[nt], acc[mt][nt], 0, 0, 0);
        }
    }
    __syncthreads();   // A segs dead

    // epilogue-1: add z0, stash pre-activations in zbuf (bf16)
    #pragma unroll
    for (int mt = 0; mt < 2; ++mt) {
        #pragma unroll
        for (int nt = 0; nt < 4; ++nt) {
            int n = n_off + nt * 16 + ln16;
            #pragma unroll
            for (int r4 = 0; r4 < 4; ++r4) {
                int row = mt * 16 + quad * 4 + r4;
                int b = row & 7, p = row >> 3;
                float z = acc[mt][nt][r4] + bf2f(z0l[((size_t)b * T + t0 + p) * 256 + n]);
                lds[row * 264 + n] = f2bf(z);
            }
        }
    }
    __syncthreads();

    // gate: g = tanh(zt) * sigmoid(zs) -> gbuf [32][136]
    {
        int r = tid >> 3;              // 0..31
        int k0 = (tid & 7) * 16;       // 0..127 step 16
        #pragma unroll
        for (int kk = 0; kk < 16; ++kk) {
            int k = k0 + kk;
            float zt = bf2f(lds[r * 264 + k]);
            float zs = bf2f(lds[r * 264 + 128 + k]);
            lds[8704 + r * 136 + k] = f2bf(tanhf_(zt) * sigmoidf_(zs));
        }
    }
    __syncthreads();

    // GEMM2: skip/res 1x1 convs, K=128
    f32x4 acc2[2][4];
    #pragma unroll
    for (int mt = 0; mt < 2; ++mt)
        #pragma unroll
        for (int nt = 0; nt < 4; ++nt)
            acc2[mt][nt] = (f32x4){0.f, 0.f, 0.f, 0.f};

    #pragma unroll
    for (int kc = 0; kc < 4; ++kc) {
        bf16x8 af[2], bfr[4];
        #pragma unroll
        for (int mt = 0; mt < 2; ++mt)
            af[mt] = *(const bf16x8*)(&lds[8704 + (mt * 16 + ln16) * 136 + kc * 32 + quad * 8]);
        #pragma unroll
        for (int nt = 0; nt < 4; ++nt)
            bfr[nt] = *(const bf16x8*)(WR + (size_t)(n_off + nt * 16 + ln16) * 128 + kc * 32 + quad * 8);
        #pragma unroll
        for (int mt = 0; mt < 2; ++mt)
            #pragma unroll
            for (int nt = 0; nt < 4; ++nt)
                acc2[mt][nt] = __builtin_amdgcn_mfma_f32_16x16x32_bf16(af[mt], bfr[nt], acc2[mt][nt], 0, 0, 0);
    }

    // epilogue-2: waves 0/1 (n<128) -> skip accum; waves 2/3 -> residual h
    #pragma unroll
    for (int mt = 0; mt < 2; ++mt) {
        #pragma unroll
        for (int nt = 0; nt < 4; ++nt) {
            int n = n_off + nt * 16 + ln16;
            int k = n & 127;
            #pragma unroll
            for (int r4 = 0; r4 < 4; ++r4) {
                int row = mt * 16 + quad * 4 + r4;
                int b = row & 7, p = row >> 3;
                size_t idx = ((size_t)b * T + t0 + p) * 128 + k;
                float v = acc2[mt][nt][r4];
                if (n < 128) {
                    skip32[idx] += v + bskip[k];
                } else {
                    float hv = v + bres[k] + h32_in[idx];
                    h32_out[idx] = hv;
                    hb_out[idx] = f2bf(hv);
                }
            }
        }
    }
}

// ---------------- MFMA conv head stage 1 (k=3 conv, padded-row output) ----------------
template<int KIN, bool OUT_BF16>
__global__ __launch_bounds__(256) void k_conv_mfma(
    const ushort* __restrict__ A, const ushort* __restrict__ Wb,
    const float* __restrict__ bias, void* __restrict__ outv,
    int b_in_off, int b_out_off, int ots, int oto)
{
    constexpr int AS = 40;
    __shared__ ushort As[66 * AS];
    __shared__ ushort Bs[3 * 128 * AS];

    const int tid  = threadIdx.x;
    const int lane = tid & 63;
    const int ln16 = lane & 15;
    const int quad = lane >> 4;
    const int wave = tid >> 6;
    const int m_off = (wave & 1) * 32;
    const int n_off = (wave >> 1) * 64;

    const int t0 = blockIdx.x * 64;
    const int n0 = blockIdx.y * 128;
    const int bz = blockIdx.z;
    const int N  = gridDim.y * 128;

    const ushort* Ab = A + (size_t)(b_in_off + bz) * T * KIN;

    f32x4 acc[2][4];
    #pragma unroll
    for (int mi = 0; mi < 2; ++mi)
        #pragma unroll
        for (int ni = 0; ni < 4; ++ni)
            acc[mi][ni] = (f32x4){0.f, 0.f, 0.f, 0.f};

    for (int cc = 0; cc < KIN / 32; ++cc) {
        for (int idx = tid; idx < 66 * 4; idx += 256) {
            int r = idx >> 2, part = idx & 3;
            int t = t0 - 1 + r;
            uint4 v = make_uint4(0u, 0u, 0u, 0u);
            if (t >= 0 && t < T)
                v = *(const uint4*)(Ab + (size_t)t * KIN + cc * 32 + part * 8);
            *(uint4*)(&As[r * AS + part * 8]) = v;
        }
        #pragma unroll
        for (int it = 0; it < 6; ++it) {
            int idx = tid + it * 256;
            int jr = idx >> 2, part = idx & 3;
            int j = jr >> 7, n = jr & 127;
            uint4 v = *(const uint4*)(Wb + (size_t)(n0 + n) * (3 * KIN) + j * KIN + cc * 32 + part * 8);
            *(uint4*)(&Bs[jr * AS + part * 8]) = v;
        }
        __syncthreads();

        #pragma unroll
        for (int j = 0; j < 3; ++j) {
            bf16x8 af[2], bf[4];
            #pragma unroll
            for (int mi = 0; mi < 2; ++mi)
                af[mi] = *(const bf16x8*)(&As[(m_off + mi * 16 + ln16 + j) * AS + quad * 8]);
            #pragma unroll
            for (int ni = 0; ni < 4; ++ni)
                bf[ni] = *(const bf16x8*)(&Bs[(j * 128 + n_off + ni * 16 + ln16) * AS + quad * 8]);
            #pragma unroll
            for (int mi = 0; mi < 2; ++mi)
                #pragma unroll
                for (int ni = 0; ni < 4; ++ni)
                    acc[mi][ni] = __builtin_amdgcn_mfma_f32_16x16x32_bf16(af[mi], bf[ni], acc[mi][ni], 0, 0, 0);
        }
        __syncthreads();
    }

    #pragma unroll
    for (int ni = 0; ni < 4; ++ni) {
        int n = n0 + n_off + ni * 16 + ln16;
        float bv = bias[n];
        #pragma unroll
        for (int mi = 0; mi < 2; ++mi) {
            #pragma unroll
            for (int r = 0; r < 4; ++r) {
                int m = m_off + mi * 16 + quad * 4 + r;
                int t = t0 + m;
                float v = fmaxf(acc[mi][ni][r] + bv, 0.f);
                size_t oi = ((size_t)(b_out_off + bz) * ots + oto + t) * N + n;
                if constexpr (OUT_BF16) ((ushort*)outv)[oi] = f2bf(v);
                else                    ((float*)outv)[oi]  = v;
            }
        }
    }
}

// ---------------- conv2 as 3-tap overlapped GEMM, double-buffered gload_lds ----------------
// A = out1p [8][2050][2048] bf16 (rows padded+zeroed at pr=0,2049)
// W = W2b [256][3*2048], out2[b][t][n] = relu(sum_taps A-row(t+j) . W-slice + b2)
// grid (16 m-tiles of 128, 8 b, 2 n-halves of 128); block 256 = 4 waves of 64x64 tiles.
#define CV2_AUS 8704      // A tile: 136 rows * 64 us
#define CV2_BUS 24576     // B tile: 384 rows * 64 us
#define CV2_BUF 33280     // per-buffer ushorts

__global__ __launch_bounds__(256) void k_conv2t(
    const ushort* __restrict__ A,     // out1p
    const ushort* __restrict__ Wb,    // W2b [256][6144]
    const float* __restrict__ bias,   // b2
    float* __restrict__ out2)         // [8][2048][256]
{
    __shared__ ushort sh[2 * CV2_BUF];   // 133120 B
    const int tid  = threadIdx.x;
    const int lane = tid & 63, ln16 = lane & 15, quad = lane >> 4;
    const int wave = tid >> 6;
    const int wm = wave >> 1, wn = wave & 1;
    const int m0 = blockIdx.x * 128;
    const int b  = blockIdx.y;
    const int n0 = blockIdx.z * 128;
    const size_t aRow0 = (size_t)b * 2050 + m0;   // padded row base (t=m0-1 at r=0)

    f32x4 acc[4][4];
    #pragma unroll
    for (int i = 0; i < 4; ++i)
        #pragma unroll
        for (int j = 0; j < 4; ++j) acc[i][j] = (f32x4){0.f, 0.f, 0.f, 0.f};

    // stage K-chunk cc into buffer d. LDS linear; global source slot-swizzled (q = p ^ (r&7))
    auto stage = [&](int d, int cc) {
        const int sb = d * CV2_BUF;
        const int k0 = cc * 64;
        #pragma unroll
        for (int ps = 0; ps < 4; ++ps) {
            int task = ps * 256 + tid;
            int r = task >> 3, p = task & 7, q = p ^ (r & 7);
            gl_lds16(A + (aRow0 + r) * 2048 + k0 + q * 8,
                     &sh[sb + ((ps * 256 + wave * 64) << 3)]);
        }
        if (tid < 64) {                       // wave 0 only: A rows 128..135
            int task = 1024 + tid;
            int r = task >> 3, p = task & 7, q = p ^ (r & 7);
            gl_lds16(A + (aRow0 + r) * 2048 + k0 + q * 8,
                     &sh[sb + (1024 << 3)]);
        }
        #pragma unroll
        for (int ps = 0; ps < 12; ++ps) {
            int task = ps * 256 + tid;
            int rb = task >> 3, p = task & 7, q = p ^ (rb & 7);
            int nl = rb & 127, tap = rb >> 7;
            gl_lds16(Wb + (size_t)(n0 + nl) * 6144 + tap * 2048 + k0 + q * 8,
                     &sh[sb + CV2_AUS + ((ps * 256 + wave * 64) << 3)]);
        }
    };

    stage(0, 0);
    __syncthreads();

    for (int cc = 0; cc < 32; ++cc) {
        if (cc < 31) stage((cc + 1) & 1, cc + 1);
        const int sb = (cc & 1) * CV2_BUF;
        #pragma unroll
        for (int j = 0; j < 3; ++j) {
            #pragma unroll
            for (int kk = 0; kk < 2; ++kk) {
                bf16x8 af[4], bfr[4];
                #pragma unroll
                for (int mt = 0; mt < 4; ++mt) {
                    int r = wm * 64 + mt * 16 + ln16 + j;
                    int s = (kk << 2) | quad;
                    af[mt] = *(const bf16x8*)(&sh[sb + r * 64 + ((s ^ (r & 7)) << 3)]);
                }
                #pragma unroll
                for (int nt = 0; nt < 4; ++nt) {
                    int rb = j * 128 + wn * 64 + nt * 16 + ln16;
                    int s = (kk << 2) | quad;
                    bfr[nt] = *(const bf16x8*)(&sh[sb + CV2_AUS + rb * 64 + ((s ^ (rb & 7)) << 3)]);
                }
                #pragma unroll
                for (int mt = 0; mt < 4; ++mt)
                    #pragma unroll
                    for (int nt = 0; nt < 4; ++nt)
                        acc[mt][nt] = __builtin_amdgcn_mfma_f32_16x16x32_bf16(af[mt], bfr[nt], acc[mt][nt], 0, 0, 0);
            }
        }
        __syncthreads();
    }

    // epilogue: bias + relu, plain f32 stores
    #pragma unroll
    for (int nt = 0; nt < 4; ++nt) {
        int n = n0 + wn * 64 + nt * 16 + ln16;
        float bv = bias[n];
        #pragma unroll
        for (int mt = 0; mt < 4; ++mt) {
            #pragma unroll
            for (int r4 = 0; r4 < 4; ++r4) {
                int m = wm * 64 + mt * 16 + quad * 4 + r4;
                int t = m0 + m;
                float v = fmaxf(acc[mt][nt][r4] + bv, 0.f);
                out2[((size_t)b * T + t) * 256 + n] = v;
            }
        }
    }
}

// ---------------- head conv3: 256 -> 1, k=1, tanh ----------------
__global__ __launch_bounds__(256) void k_conv3(
    const float* __restrict__ out2, const float* __restrict__ W3,
    const float* __restrict__ b3, float* __restrict__ out)
{
    int wid = threadIdx.x >> 6, lane = threadIdx.x & 63;
    int pos = blockIdx.x * 4 + wid;
    float4 v = *(const float4*)(out2 + (size_t)pos * 256 + lane * 4);
    float4 w = *(const float4*)(W3 + lane * 4);
    float sum = v.x * w.x + v.y * w.y + v.z * w.z + v.w * w.w;
    #pragma unroll
    for (int off = 32; off > 0; off >>= 1) sum += __shfl_down(sum, off);
    if (lane == 0) out[pos] = tanhf_(sum + b3[0]);
}

extern "C" void kernel_launch(void* const* d_in, const int* in_sizes, int n_in,
                              void* d_out, int out_size, void* d_ws, size_t ws_size,
                              hipStream_t stream)
{
    const float* x     = (const float*)d_in[0];
    const float* cond  = (const float*)d_in[1];
    const float* Wc    = (const float*)d_in[2];
    const float* bc    = (const float*)d_in[3];
    const float* Wt    = (const float*)d_in[4];
    const float* bt    = (const float*)d_in[5];
    const float* Ws    = (const float*)d_in[6];
    const float* bs    = (const float*)d_in[7];
    const float* Dt    = (const float*)d_in[8];
    const float* Bt    = (const float*)d_in[9];
    const float* Ds    = (const float*)d_in[10];
    const float* Bs    = (const float*)d_in[11];
    const float* Wskip = (const float*)d_in[12];
    const float* bskip = (const float*)d_in[13];
    const float* Wres  = (const float*)d_in[14];
    const float* bres  = (const float*)d_in[15];
    const float* W1    = (const float*)d_in[16];
    const float* b1    = (const float*)d_in[17];
    const float* W2    = (const float*)d_in[18];
    const float* b2    = (const float*)d_in[19];
    const float* W3    = (const float*)d_in[20];
    const float* b3    = (const float*)d_in[21];
    float* out = (float*)d_out;

    float* ws = (float*)d_ws;
    float*  skip32 = ws;                       // 2M f32
    float*  h32a   = ws + 2097152;             // 2M f32
    float*  h32b   = ws + 4194304;             // 2M f32
    float*  out2   = ws + 6291456;             // 4M f32 (byte 25.2M .. 41.9M)
    ushort* u      = (ushort*)(ws + 10485760); // byte 41.94 MB
    ushort* hba    = u;                        // 2M us (dead after layers)
    ushort* hbb    = u + 2097152;              // 2M us (dead after layers)
    ushort* WGb    = u + 4194304;              // 983,040 us
    ushort* WRb    = u + 5177344;              // 327,680 us
    ushort* W1b    = u + 5505024;              // 786,432 us
    ushort* W2b    = u + 6291456;              // 1,572,864 us (ends u+7,864,320)
    ushort* skipb  = u;                        // 2M us, reuses hba (dead by then)
    ushort* z0     = u + 9961472;              // 5*8*T*256 = 20,971,520 us (dead at head)
    // padded conv1 output [8][2050][2048] bf16 = 33,587,200 us, overlaps z0 (dead)
    ushort* out1p  = u + 7864320;              // ends byte 124.85 MB (< proven 129 MB)

    k_init<<<8192, 256, 0, stream>>>(x, Wc, bc, h32a, hba, skip32);
    k_prep_wg<<<dim3(256, NLAYER), 384, 0, stream>>>(Wt, Ws, WGb);
    k_prep_wr<<<dim3(256, NLAYER), 128, 0, stream>>>(Wskip, Wres, WRb);
    k_prep_w<128><<<2048, 384, 0, stream>>>(W1, W1b, 2048);
    k_prep_w<2048><<<256, 1024, 0, stream>>>(W2, W2b, 256);

    static const int DIL[NLAYER] = {1, 2, 4, 8, 16, 32, 64, 128, 256, 512};
    float*  h32in = h32a;  float*  h32out = h32b;
    ushort* hbin  = hba;   ushort* hbout  = hbb;

    for (int chunk = 0; chunk < 2; ++chunk) {
        int l0 = chunk * 5;
        k_cond<<<dim3(T / 8, 5), 256, 0, stream>>>(cond, Dt, Bt, Ds, Bs, bt, bs, z0, l0);
        for (int l = l0; l < l0 + 5; ++l) {
            k_gate<<<512, 256, 0, stream>>>(
                h32in, h32out, hbin, hbout, skip32,
                WGb + (size_t)l * 256 * 384,
                WRb + (size_t)l * 256 * 128,
                z0 + (size_t)(l - l0) * 8 * T * 256,
                bskip + l * 128, bres + l * 128,
                DIL[l]);
            float* tf = h32in; h32in = h32out; h32out = tf;
            ushort* tu = hbin; hbin = hbout; hbout = tu;
        }
    }

    // head: skip -> bf16, pad rows zeroed, conv1 (padded out), conv2 GEMM, conv3
    k_f32_to_bf16<<<(BATCH * T * C + 255) / 256, 256, 0, stream>>>(skip32, skipb, BATCH * T * C);
    k_zero_pad<<<64, 256, 0, stream>>>(out1p);
    k_conv_mfma<128, true><<<dim3(T / 64, 16, BATCH), 256, 0, stream>>>(
        skipb, W1b, b1, out1p, 0, 0, 2050, 1);
    k_conv2t<<<dim3(16, 8, 2), 256, 0, stream>>>(out1p, W2b, b2, out2);
    k_conv3<<<(BATCH * T) / 4, 256, 0, stream>>>(out2, W3, b3, out);
}